// Round 2
// baseline (855.558 us; speedup 1.0000x reference)
//
#include <hip/hip_runtime.h>
#include <hip/hip_bf16.h>
#include <cstdint>

// ---------------------------------------------------------------------------
// Edge2NodeProp: e = (rbf @ W_rbf^T) * x ; h = segment_sum(e, idx_i);
//                h = swish(h@W1^T+b1) x3; out = h @ W_out^T
// All float32 buffers (reference dtypes). idx int32. Output (N,1) f32.
// Workspace: N*64 f32 accumulator (25.6 MB).
// ---------------------------------------------------------------------------

// Phase 1: edge gating + scatter-add.  One wave per edge, lane = dim.
__global__ __launch_bounds__(256) void edge_kernel(
    const float* __restrict__ x,     // (E,64)
    const float* __restrict__ rbf,   // (E,16)
    const int*   __restrict__ idx,   // (E,)
    const float* __restrict__ Wrbf,  // (64,16)
    float* __restrict__ hacc,        // (N,64)
    int n_edges, int n_nodes)
{
    const int lane   = threadIdx.x & 63;
    const int wave   = blockIdx.x * (blockDim.x >> 6) + (threadIdx.x >> 6);
    const int nwaves = gridDim.x * (blockDim.x >> 6);

    // Per-lane W_rbf row (16 f32 = 64B contiguous) -> 16 regs.
    float w[16];
    {
        const float4* wp = (const float4*)(Wrbf + (size_t)lane * 16);
        float4 a = wp[0], b = wp[1], c = wp[2], d = wp[3];
        w[0]=a.x; w[1]=a.y; w[2]=a.z; w[3]=a.w;
        w[4]=b.x; w[5]=b.y; w[6]=b.z; w[7]=b.w;
        w[8]=c.x; w[9]=c.y; w[10]=c.z; w[11]=c.w;
        w[12]=d.x; w[13]=d.y; w[14]=d.z; w[15]=d.w;
    }

    for (int e = wave; e < n_edges; e += nwaves) {
        const int node = idx[e];
        const float4* rp = (const float4*)(rbf + (size_t)e * 16);
        float4 r0 = rp[0], r1 = rp[1], r2 = rp[2], r3 = rp[3];
        float rv[16] = { r0.x, r0.y, r0.z, r0.w,
                         r1.x, r1.y, r1.z, r1.w,
                         r2.x, r2.y, r2.z, r2.w,
                         r3.x, r3.y, r3.z, r3.w };

        float g = 0.0f;
#pragma unroll
        for (int r = 0; r < 16; ++r) g = fmaf(rv[r], w[r], g);

        const float xv = x[(size_t)e * 64 + lane];
        if ((unsigned)node < (unsigned)n_nodes) {
            atomicAdd(&hacc[(size_t)node * 64 + lane], g * xv);
        }
    }
}

// ---------------------------------------------------------------------------
// Phase 2: node MLP.  One wave per node, lane = dim.
// Weights staged transposed into LDS: WT[k*64+d] = W[d*64+k]; lane-d reads at
// fixed k hit banks (d%32): 2-way aliasing = free. h[k] broadcast via
// v_readlane (constant k after full unroll).
// ---------------------------------------------------------------------------
__device__ __forceinline__ float mlp_layer(const float* __restrict__ WT,
                                           const float* __restrict__ bias,
                                           float h, int lane)
{
    float acc = bias[lane];
#pragma unroll
    for (int k = 0; k < 64; ++k) {
        const float wk = WT[k * 64 + lane];
        const float hk = __int_as_float(
            __builtin_amdgcn_readlane(__float_as_int(h), k));
        acc = fmaf(wk, hk, acc);
    }
    return acc / (1.0f + __expf(-acc));   // swish
}

__global__ __launch_bounds__(256) void node_kernel(
    const float* __restrict__ hacc,   // (N,64)
    const float* __restrict__ W1, const float* __restrict__ b1,
    const float* __restrict__ W2, const float* __restrict__ b2,
    const float* __restrict__ W3, const float* __restrict__ b3,
    const float* __restrict__ Wout,   // (1,64)
    float* __restrict__ out,          // (N,1)
    int n_nodes)
{
    __shared__ float WT[3][64 * 64];  // 48 KiB
    __shared__ float bs[3][64];
    __shared__ float wo[64];

    const int t = threadIdx.x;
    for (int i = t; i < 64 * 64; i += 256) {
        const int d = i & 63;
        const int k = i >> 6;
        WT[0][k * 64 + d] = W1[d * 64 + k];
        WT[1][k * 64 + d] = W2[d * 64 + k];
        WT[2][k * 64 + d] = W3[d * 64 + k];
    }
    if (t < 64) {
        bs[0][t] = b1[t];
        bs[1][t] = b2[t];
        bs[2][t] = b3[t];
        wo[t]    = Wout[t];
    }
    __syncthreads();

    const int lane   = t & 63;
    const int wave   = blockIdx.x * (blockDim.x >> 6) + (t >> 6);
    const int nwaves = gridDim.x * (blockDim.x >> 6);

    for (int node = wave; node < n_nodes; node += nwaves) {
        float h = hacc[(size_t)node * 64 + lane];
        h = mlp_layer(WT[0], bs[0], h, lane);
        h = mlp_layer(WT[1], bs[1], h, lane);
        h = mlp_layer(WT[2], bs[2], h, lane);

        float v = wo[lane] * h;
#pragma unroll
        for (int off = 32; off >= 1; off >>= 1) v += __shfl_xor(v, off, 64);

        if (lane == 0) out[node] = v;
    }
}

// ---------------------------------------------------------------------------
extern "C" void kernel_launch(void* const* d_in, const int* in_sizes, int n_in,
                              void* d_out, int out_size, void* d_ws, size_t ws_size,
                              hipStream_t stream)
{
    const float* x    = (const float*)d_in[0];
    const float* rbf  = (const float*)d_in[1];
    const int*   idx  = (const int*)d_in[2];
    const float* Wrbf = (const float*)d_in[4];
    const float* W1   = (const float*)d_in[5];
    const float* b1   = (const float*)d_in[6];
    const float* W2   = (const float*)d_in[7];
    const float* b2   = (const float*)d_in[8];
    const float* W3   = (const float*)d_in[9];
    const float* b3   = (const float*)d_in[10];
    const float* Wout = (const float*)d_in[11];

    const int n_edges = in_sizes[0] / 64;
    const int n_nodes = out_size;   // OUT_DIM == 1

    float* hacc = (float*)d_ws;     // N*64 f32 = 25.6 MB

    hipMemsetAsync(hacc, 0, (size_t)n_nodes * 64 * sizeof(float), stream);

    edge_kernel<<<8192, 256, 0, stream>>>(x, rbf, idx, Wrbf, hacc,
                                          n_edges, n_nodes);

    node_kernel<<<2048, 256, 0, stream>>>(hacc, W1, b1, W2, b2, W3, b3, Wout,
                                          (float*)d_out, n_nodes);
}